// Round 1
// baseline (4821.700 us; speedup 1.0000x reference)
//
#include <hip/hip_runtime.h>
#include <stdint.h>

#define TT 256
#define BB 64
#define DD 1024
#define HH 1024
#define G3 3072

typedef __attribute__((ext_vector_type(8))) short short8;
typedef __attribute__((ext_vector_type(4))) float f32x4;

__device__ __forceinline__ unsigned short f2bf(float f) {
  union { float f; unsigned int i; } v; v.f = f;
  unsigned int x = v.i;
  return (unsigned short)((x + 0x7fffu + ((x >> 16) & 1u)) >> 16);
}
__device__ __forceinline__ float bf2f(unsigned short u) {
  union { unsigned int i; float f; } v; v.i = ((unsigned int)u) << 16; return v.f;
}
__device__ __forceinline__ f32x4 mfma16(short8 a, short8 b, f32x4 c) {
  return __builtin_amdgcn_mfma_f32_16x16x32_bf16(a, b, c, 0, 0, 0);
}
__device__ __forceinline__ void gload_lds16(const void* g, void* l) {
  __builtin_amdgcn_global_load_lds((const __attribute__((address_space(1))) void*)g,
                                   (__attribute__((address_space(3))) void*)l,
                                   16, 0, 0);
}

// ---------------- f32 -> bf16 convert (vectorized) ----------------
__global__ void k_cvt_bf16(const float* __restrict__ in, unsigned short* __restrict__ out, int n4) {
  int i = blockIdx.x * blockDim.x + threadIdx.x;
  int stride = gridDim.x * blockDim.x;
  for (; i < n4; i += stride) {
    float4 v = ((const float4*)in)[i];
    ushort4 o;
    o.x = f2bf(v.x); o.y = f2bf(v.y); o.z = f2bf(v.z); o.w = f2bf(v.w);
    ((ushort4*)out)[i] = o;
  }
}

// ---------------- context projections + bias fold: E[64][3072] ----------------
// E[b][g] = b_ih[g] + b_ch[g] + b_zh[g] + (g<2H ? b_hh[g] : 0)
//           + dot(cj[b], w_ch[g]) + dot(he[b], w_zh[g])
__global__ __launch_bounds__(256) void k_ctx(
    const unsigned short* __restrict__ cjb, const unsigned short* __restrict__ heb,
    const unsigned short* __restrict__ Wchb, const unsigned short* __restrict__ Wzhb,
    const float* __restrict__ b_ih, const float* __restrict__ b_hh,
    const float* __restrict__ b_ch, const float* __restrict__ b_zh,
    float* __restrict__ E) {
  __shared__ f32x4 red[4][4][64];   // 16 KB
  int n0 = blockIdx.x * 16;         // 192 blocks
  int tid = threadIdx.x;
  int w = tid >> 6, l = tid & 63, lo = l & 15, hi = l >> 4;
  f32x4 acc[4];
#pragma unroll
  for (int r = 0; r < 4; r++) acc[r] = (f32x4){0.f, 0.f, 0.f, 0.f};
  // wave w covers concat-K range [w*512, w*512+512): waves 0,1 -> cj/Wch, waves 2,3 -> he/Wzh
#pragma unroll 4
  for (int kk = 0; kk < 16; kk++) {
    int k = w * 512 + kk * 32;
    const unsigned short* Asrc = (k < 1024) ? cjb : heb;
    const unsigned short* Bsrc = (k < 1024) ? Wchb : Wzhb;
    int kw = (k < 1024) ? k : (k - 1024);
    int kof = kw + hi * 8;
    short8 bf = *(const short8*)(Bsrc + (size_t)(n0 + lo) * 1024 + kof);
#pragma unroll
    for (int r = 0; r < 4; r++) {
      short8 af = *(const short8*)(Asrc + (size_t)(r * 16 + lo) * 1024 + kof);
      acc[r] = mfma16(af, bf, acc[r]);
    }
  }
#pragma unroll
  for (int r = 0; r < 4; r++) red[w][r][l] = acc[r];
  __syncthreads();
  f32x4 s = red[0][w][l];
#pragma unroll
  for (int w2 = 1; w2 < 4; w2++) {
    f32x4 p = red[w2][w][l];
    s[0] += p[0]; s[1] += p[1]; s[2] += p[2]; s[3] += p[3];
  }
  int g = n0 + lo;
  float bias = b_ih[g] + b_ch[g] + b_zh[g] + ((g < 2048) ? b_hh[g] : 0.0f);
#pragma unroll
  for (int j = 0; j < 4; j++) {
    int b = w * 16 + hi * 4 + j;
    E[(size_t)b * G3 + g] = s[j] + bias;
  }
}

// ---------------- gi GEMM: gi[t*64+b][g] = sum_d X[t*64+b][d] * Wih[g][d]  (bf16 out, no bias) --------
__global__ __launch_bounds__(256) void k_gemm_gi(
    const unsigned short* __restrict__ Xb,   // [16384][1024] bf16
    const unsigned short* __restrict__ Wb,   // [3072][1024] bf16
    unsigned short* __restrict__ gi) {       // [16384][3072] bf16
  __shared__ unsigned short As[128 * 32];
  __shared__ unsigned short Bs[128 * 32];
  int bid = blockIdx.x;
  int mt = bid & 127;   // M fastest: consecutive blocks share the W n-tile (L2)
  int nt = bid >> 7;
  int m0 = mt * 128, n0 = nt * 128;
  int tid = threadIdx.x;
  int w = tid >> 6, l = tid & 63, lo = l & 15, hi = l >> 4;
  int wr = w >> 1, wc = w & 1;
  f32x4 acc[4][4];
#pragma unroll
  for (int i = 0; i < 4; i++)
#pragma unroll
    for (int j = 0; j < 4; j++) acc[i][j] = (f32x4){0.f, 0.f, 0.f, 0.f};
  int srow = tid >> 2;          // 0..63
  int scol = (tid & 3) * 8;     // element offset within 32-wide K
  for (int kt = 0; kt < 32; kt++) {
    int k0 = kt * 32;
    __syncthreads();            // LDS WAR
    gload_lds16(Xb + (size_t)(m0 + srow) * 1024 + k0 + scol, As + srow * 32 + scol);
    gload_lds16(Xb + (size_t)(m0 + 64 + srow) * 1024 + k0 + scol, As + (64 + srow) * 32 + scol);
    gload_lds16(Wb + (size_t)(n0 + srow) * 1024 + k0 + scol, Bs + srow * 32 + scol);
    gload_lds16(Wb + (size_t)(n0 + 64 + srow) * 1024 + k0 + scol, Bs + (64 + srow) * 32 + scol);
    asm volatile("s_waitcnt vmcnt(0)" ::: "memory");
    __syncthreads();
    short8 a[4], b[4];
#pragma unroll
    for (int i = 0; i < 4; i++) a[i] = *(const short8*)(As + (wr * 64 + i * 16 + lo) * 32 + hi * 8);
#pragma unroll
    for (int i = 0; i < 4; i++) b[i] = *(const short8*)(Bs + (wc * 64 + i * 16 + lo) * 32 + hi * 8);
#pragma unroll
    for (int i = 0; i < 4; i++)
#pragma unroll
      for (int j = 0; j < 4; j++) acc[i][j] = mfma16(a[i], b[j], acc[i][j]);
  }
#pragma unroll
  for (int i = 0; i < 4; i++)
#pragma unroll
    for (int j = 0; j < 4; j++)
#pragma unroll
      for (int e = 0; e < 4; e++) {
        int r = m0 + wr * 64 + i * 16 + hi * 4 + e;
        int c = n0 + wc * 64 + j * 16 + lo;
        gi[(size_t)r * G3 + c] = f2bf(acc[i][j][e]);
      }
}

// ---------------- persistent recurrence kernel ----------------
// 64 workgroups; wg owns h columns [wg*16, wg*16+16). 4 waves split K=1024 by 256.
__global__ __launch_bounds__(256) void k_rnn(
    const unsigned short* __restrict__ gi,    // [256*64][3072] bf16 (no E)
    const unsigned short* __restrict__ Whhb,  // [3072][1024] bf16
    const float* __restrict__ E,              // [64][3072]
    const float* __restrict__ b_hh,           // [3072]
    const float* __restrict__ h0,             // [64][1024]
    const int* __restrict__ length,           // [64]
    unsigned short* __restrict__ hbuf,        // [2][64][1024] bf16
    float* __restrict__ out,                  // [256][64][1024]
    float* __restrict__ hn,                   // [64][1024]
    unsigned int* __restrict__ ctr) {
  __shared__ f32x4 red[3072];   // [wave][12 tiles][64 lanes] = 48 KB
  __shared__ float hp0[2][16];  // double-buffered h_prev[batch row 0][slice]
  int wg = blockIdx.x;
  int j0 = wg * 16;
  int tid = threadIdx.x;
  int w = tid >> 6, l = tid & 63, lo = l & 15, hi = l >> 4;
  int col = j0 + lo;

  // ---- preload constants ----
  float Ereg[3][4];
  int len[4];
#pragma unroll
  for (int s = 0; s < 3; s++)
#pragma unroll
    for (int j = 0; j < 4; j++)
      Ereg[s][j] = E[(size_t)(16 * w + hi * 4 + j) * G3 + s * 1024 + col];
#pragma unroll
  for (int j = 0; j < 4; j++) len[j] = length[16 * w + hi * 4 + j];
  float bhhn = b_hh[2048 + col];
  float hown[4];
#pragma unroll
  for (int j = 0; j < 4; j++) {
    int b = 16 * w + hi * 4 + j;
    float v = h0[(size_t)b * 1024 + col];
    hown[j] = v;
    hbuf[(size_t)b * 1024 + col] = f2bf(v);   // slot 0 init
  }
  if (w == 0 && hi == 0) hp0[0][lo] = h0[j0 + lo];  // batch row 0
  const unsigned short* wrow0 = Whhb + (size_t)(0 * 1024 + j0 + lo) * 1024;
  const unsigned short* wrow1 = Whhb + (size_t)(1 * 1024 + j0 + lo) * 1024;
  const unsigned short* wrow2 = Whhb + (size_t)(2 * 1024 + j0 + lo) * 1024;
  int kwbase = w * 256;
  __syncthreads();

  for (int t = 0; t < TT; t++) {
    // ---- 1. prefetch gi for this step (independent of h; overlaps barrier wait) ----
    float gir[3][4];
    {
      const unsigned short* gb = gi + (size_t)t * 64 * G3;
#pragma unroll
      for (int s = 0; s < 3; s++)
#pragma unroll
        for (int j = 0; j < 4; j++)
          gir[s][j] = bf2f(gb[(size_t)(16 * w + hi * 4 + j) * G3 + s * 1024 + col]);
    }
    // ---- 2. grid barrier: publish h_{t-1}, wait for all 64 wgs ----
    __threadfence();
    __syncthreads();
    if (tid == 0) {
      __hip_atomic_fetch_add(ctr, 1u, __ATOMIC_RELEASE, __HIP_MEMORY_SCOPE_AGENT);
      unsigned int tgt = 64u * (unsigned int)(t + 1);
      while (__hip_atomic_load(ctr, __ATOMIC_RELAXED, __HIP_MEMORY_SCOPE_AGENT) < tgt)
        __builtin_amdgcn_s_sleep(1);
    }
    __syncthreads();
    __threadfence();   // acquire side
    // ---- 3. partial GEMM: (h_{t-1} @ Whh^T) for 3 strips x 4 row-tiles, K-range [kwbase, +256) ----
    const unsigned short* hb = hbuf + (size_t)(t & 1) * (BB * HH);
    f32x4 acc[4][3];
#pragma unroll
    for (int r = 0; r < 4; r++)
#pragma unroll
      for (int s = 0; s < 3; s++) acc[r][s] = (f32x4){0.f, 0.f, 0.f, 0.f};
#pragma unroll
    for (int kk = 0; kk < 8; kk++) {
      int k = kwbase + kk * 32 + hi * 8;
      short8 bf0 = *(const short8*)(wrow0 + k);
      short8 bf1 = *(const short8*)(wrow1 + k);
      short8 bf2 = *(const short8*)(wrow2 + k);
#pragma unroll
      for (int r = 0; r < 4; r++) {
        short8 a = *(const short8*)(hb + (size_t)(r * 16 + lo) * 1024 + k);
        acc[r][0] = mfma16(a, bf0, acc[r][0]);
        acc[r][1] = mfma16(a, bf1, acc[r][1]);
        acc[r][2] = mfma16(a, bf2, acc[r][2]);
      }
    }
    // ---- 4. cross-wave K reduction in LDS; wave w owns row-tile rt=w ----
#pragma unroll
    for (int r = 0; r < 4; r++)
#pragma unroll
      for (int s = 0; s < 3; s++) red[(w * 12 + r * 3 + s) * 64 + l] = acc[r][s];
    __syncthreads();
    f32x4 fin[3];
#pragma unroll
    for (int s = 0; s < 3; s++) {
      f32x4 v = red[(0 * 12 + w * 3 + s) * 64 + l];
#pragma unroll
      for (int w2 = 1; w2 < 4; w2++) {
        f32x4 p = red[(w2 * 12 + w * 3 + s) * 64 + l];
        v[0] += p[0]; v[1] += p[1]; v[2] += p[2]; v[3] += p[3];
      }
      fin[s] = v;
    }
    // ---- 5. gates + state update for rows 16w..16w+15, cols slice ----
    float hp0col = hp0[t & 1][lo];
    unsigned short* hbn = hbuf + (size_t)((t + 1) & 1) * (BB * HH);
    float hnew0 = 0.f;
#pragma unroll
    for (int j = 0; j < 4; j++) {
      float R = fin[0][j] + gir[0][j] + Ereg[0][j];
      float I = fin[1][j] + gir[1][j] + Ereg[1][j];
      float rg = 1.f / (1.f + __expf(-R));
      float ig = 1.f / (1.f + __expf(-I));
      float nx = gir[2][j] + Ereg[2][j] + rg * (fin[2][j] + bhhn);
      nx = fminf(15.f, fmaxf(-15.f, nx));
      float e2 = __expf(2.f * nx);
      float ng = (e2 - 1.f) / (e2 + 1.f);
      float hy = ng + ig * (hown[j] - ng);
      float hv = (t < len[j]) ? hy : hp0col;   // masked rows copy h_{t-1}[0]
      hown[j] = hv;
      int b = 16 * w + hi * 4 + j;
      out[(size_t)t * (BB * HH) + (size_t)b * 1024 + col] = hv;
      hbn[(size_t)b * 1024 + col] = f2bf(hv);
      if (t == TT - 1) hn[(size_t)b * 1024 + col] = hv;
      if (j == 0) hnew0 = hv;
    }
    if (w == 0 && hi == 0) hp0[(t + 1) & 1][lo] = hnew0;  // publish new row-0 slice
  }
}

// ---------------- host ----------------
extern "C" void kernel_launch(void* const* d_in, const int* in_sizes, int n_in,
                              void* d_out, int out_size, void* d_ws, size_t ws_size,
                              hipStream_t stream) {
  const float* input_ = (const float*)d_in[0];
  const int* length   = (const int*)d_in[1];
  const float* h0     = (const float*)d_in[2];
  const float* cj     = (const float*)d_in[3];
  const float* he     = (const float*)d_in[4];
  const float* w_ih   = (const float*)d_in[5];
  const float* w_hh   = (const float*)d_in[6];
  const float* w_ch   = (const float*)d_in[7];
  const float* w_zh   = (const float*)d_in[8];
  const float* b_ih   = (const float*)d_in[9];
  const float* b_hh   = (const float*)d_in[10];
  const float* b_ch   = (const float*)d_in[11];
  const float* b_zh   = (const float*)d_in[12];

  char* ws = (char*)d_ws;
  const size_t OFF_XB   = 256;
  const size_t OFF_WIHB = OFF_XB + 33554432ull;
  const size_t OFF_WHHB = OFF_WIHB + 6291456ull;
  const size_t OFF_WCHB = OFF_WHHB + 6291456ull;
  const size_t OFF_WZHB = OFF_WCHB + 6291456ull;
  const size_t OFF_CJB  = OFF_WZHB + 6291456ull;
  const size_t OFF_HEB  = OFF_CJB + 131072ull;
  const size_t OFF_E    = OFF_HEB + 131072ull;
  const size_t OFF_GI   = OFF_E + 786432ull;
  const size_t OFF_HBUF = OFF_GI + 100663296ull;

  unsigned int* ctr     = (unsigned int*)ws;
  unsigned short* Xb    = (unsigned short*)(ws + OFF_XB);
  unsigned short* Wihb  = (unsigned short*)(ws + OFF_WIHB);
  unsigned short* Whhb  = (unsigned short*)(ws + OFF_WHHB);
  unsigned short* Wchb  = (unsigned short*)(ws + OFF_WCHB);
  unsigned short* Wzhb  = (unsigned short*)(ws + OFF_WZHB);
  unsigned short* cjb   = (unsigned short*)(ws + OFF_CJB);
  unsigned short* heb   = (unsigned short*)(ws + OFF_HEB);
  float* E              = (float*)(ws + OFF_E);
  unsigned short* gi    = (unsigned short*)(ws + OFF_GI);
  unsigned short* hbuf  = (unsigned short*)(ws + OFF_HBUF);

  float* out = (float*)d_out;
  float* hn  = out + 16777216;   // T*B*H

  hipMemsetAsync(ctr, 0, 256, stream);
  k_cvt_bf16<<<2048, 256, 0, stream>>>(input_, Xb, 16777216 / 4);
  k_cvt_bf16<<<1024, 256, 0, stream>>>(w_ih, Wihb, 3145728 / 4);
  k_cvt_bf16<<<1024, 256, 0, stream>>>(w_hh, Whhb, 3145728 / 4);
  k_cvt_bf16<<<1024, 256, 0, stream>>>(w_ch, Wchb, 3145728 / 4);
  k_cvt_bf16<<<1024, 256, 0, stream>>>(w_zh, Wzhb, 3145728 / 4);
  k_cvt_bf16<<<64, 256, 0, stream>>>(cj, cjb, 65536 / 4);
  k_cvt_bf16<<<64, 256, 0, stream>>>(he, heb, 65536 / 4);
  k_ctx<<<192, 256, 0, stream>>>(cjb, heb, Wchb, Wzhb, b_ih, b_hh, b_ch, b_zh, E);
  k_gemm_gi<<<3072, 256, 0, stream>>>(Xb, Wihb, gi);
  k_rnn<<<64, 256, 0, stream>>>(gi, Whhb, E, b_hh, h0, length, hbuf, out, hn, ctr);
}

// Round 2
// 3174.401 us; speedup vs baseline: 1.5189x; 1.5189x over previous
//
#include <hip/hip_runtime.h>
#include <stdint.h>

#define TT 256
#define BB 64
#define DD 1024
#define HH 1024
#define G3 3072

typedef unsigned long long ull;
typedef __attribute__((ext_vector_type(8))) short short8;
typedef __attribute__((ext_vector_type(4))) float f32x4;

__device__ __forceinline__ unsigned short f2bf(float f) {
  union { float f; unsigned int i; } v; v.f = f;
  unsigned int x = v.i;
  return (unsigned short)((x + 0x7fffu + ((x >> 16) & 1u)) >> 16);
}
__device__ __forceinline__ float bf2f(unsigned short u) {
  union { unsigned int i; float f; } v; v.i = ((unsigned int)u) << 16; return v.f;
}
__device__ __forceinline__ f32x4 mfma16(short8 a, short8 b, f32x4 c) {
  return __builtin_amdgcn_mfma_f32_16x16x32_bf16(a, b, c, 0, 0, 0);
}
__device__ __forceinline__ void gload_lds16(const void* g, void* l) {
  __builtin_amdgcn_global_load_lds((const __attribute__((address_space(1))) void*)g,
                                   (__attribute__((address_space(3))) void*)l,
                                   16, 0, 0);
}

// ---------------- f32 -> bf16 convert (vectorized) ----------------
__global__ void k_cvt_bf16(const float* __restrict__ in, unsigned short* __restrict__ out, int n4) {
  int i = blockIdx.x * blockDim.x + threadIdx.x;
  int stride = gridDim.x * blockDim.x;
  for (; i < n4; i += stride) {
    float4 v = ((const float4*)in)[i];
    ushort4 o;
    o.x = f2bf(v.x); o.y = f2bf(v.y); o.z = f2bf(v.z); o.w = f2bf(v.w);
    ((ushort4*)out)[i] = o;
  }
}

// ---------------- context projections + bias fold: E[64][3072] ----------------
// E[b][g] = b_ih[g] + b_ch[g] + b_zh[g] + (g<2H ? b_hh[g] : 0)
//           + dot(cj[b], w_ch[g]) + dot(he[b], w_zh[g])
__global__ __launch_bounds__(256) void k_ctx(
    const unsigned short* __restrict__ cjb, const unsigned short* __restrict__ heb,
    const unsigned short* __restrict__ Wchb, const unsigned short* __restrict__ Wzhb,
    const float* __restrict__ b_ih, const float* __restrict__ b_hh,
    const float* __restrict__ b_ch, const float* __restrict__ b_zh,
    float* __restrict__ E) {
  __shared__ f32x4 red[4][4][64];   // 16 KB
  int n0 = blockIdx.x * 16;         // 192 blocks
  int tid = threadIdx.x;
  int w = tid >> 6, l = tid & 63, lo = l & 15, hi = l >> 4;
  f32x4 acc[4];
#pragma unroll
  for (int r = 0; r < 4; r++) acc[r] = (f32x4){0.f, 0.f, 0.f, 0.f};
#pragma unroll 4
  for (int kk = 0; kk < 16; kk++) {
    int k = w * 512 + kk * 32;
    const unsigned short* Asrc = (k < 1024) ? cjb : heb;
    const unsigned short* Bsrc = (k < 1024) ? Wchb : Wzhb;
    int kw = (k < 1024) ? k : (k - 1024);
    int kof = kw + hi * 8;
    short8 bf = *(const short8*)(Bsrc + (size_t)(n0 + lo) * 1024 + kof);
#pragma unroll
    for (int r = 0; r < 4; r++) {
      short8 af = *(const short8*)(Asrc + (size_t)(r * 16 + lo) * 1024 + kof);
      acc[r] = mfma16(af, bf, acc[r]);
    }
  }
#pragma unroll
  for (int r = 0; r < 4; r++) red[w][r][l] = acc[r];
  __syncthreads();
  f32x4 s = red[0][w][l];
#pragma unroll
  for (int w2 = 1; w2 < 4; w2++) {
    f32x4 p = red[w2][w][l];
    s[0] += p[0]; s[1] += p[1]; s[2] += p[2]; s[3] += p[3];
  }
  int g = n0 + lo;
  float bias = b_ih[g] + b_ch[g] + b_zh[g] + ((g < 2048) ? b_hh[g] : 0.0f);
#pragma unroll
  for (int j = 0; j < 4; j++) {
    int b = w * 16 + hi * 4 + j;
    E[(size_t)b * G3 + g] = s[j] + bias;
  }
}

// ---------------- gi GEMM + E fold: giE[t*64+b][g] = X@Wih^T + E[b][g] (bf16) --------
__global__ __launch_bounds__(256) void k_gemm_gi(
    const unsigned short* __restrict__ Xb,   // [16384][1024] bf16
    const unsigned short* __restrict__ Wb,   // [3072][1024] bf16
    const float* __restrict__ E,             // [64][3072] f32
    unsigned short* __restrict__ gi) {       // [16384][3072] bf16
  __shared__ unsigned short As[128 * 32];
  __shared__ unsigned short Bs[128 * 32];
  int bid = blockIdx.x;
  int mt = bid & 127;
  int nt = bid >> 7;
  int m0 = mt * 128, n0 = nt * 128;
  int tid = threadIdx.x;
  int w = tid >> 6, l = tid & 63, lo = l & 15, hi = l >> 4;
  int wr = w >> 1, wc = w & 1;
  f32x4 acc[4][4];
#pragma unroll
  for (int i = 0; i < 4; i++)
#pragma unroll
    for (int j = 0; j < 4; j++) acc[i][j] = (f32x4){0.f, 0.f, 0.f, 0.f};
  int srow = tid >> 2;
  int scol = (tid & 3) * 8;
  for (int kt = 0; kt < 32; kt++) {
    int k0 = kt * 32;
    __syncthreads();
    gload_lds16(Xb + (size_t)(m0 + srow) * 1024 + k0 + scol, As + srow * 32 + scol);
    gload_lds16(Xb + (size_t)(m0 + 64 + srow) * 1024 + k0 + scol, As + (64 + srow) * 32 + scol);
    gload_lds16(Wb + (size_t)(n0 + srow) * 1024 + k0 + scol, Bs + srow * 32 + scol);
    gload_lds16(Wb + (size_t)(n0 + 64 + srow) * 1024 + k0 + scol, Bs + (64 + srow) * 32 + scol);
    asm volatile("s_waitcnt vmcnt(0)" ::: "memory");
    __syncthreads();
    short8 a[4], b[4];
#pragma unroll
    for (int i = 0; i < 4; i++) a[i] = *(const short8*)(As + (wr * 64 + i * 16 + lo) * 32 + hi * 8);
#pragma unroll
    for (int i = 0; i < 4; i++) b[i] = *(const short8*)(Bs + (wc * 64 + i * 16 + lo) * 32 + hi * 8);
#pragma unroll
    for (int i = 0; i < 4; i++)
#pragma unroll
      for (int j = 0; j < 4; j++) acc[i][j] = mfma16(a[i], b[j], acc[i][j]);
  }
#pragma unroll
  for (int i = 0; i < 4; i++)
#pragma unroll
    for (int j = 0; j < 4; j++)
#pragma unroll
      for (int e = 0; e < 4; e++) {
        int r = m0 + wr * 64 + i * 16 + hi * 4 + e;
        int c = n0 + wc * 64 + j * 16 + lo;
        float v = acc[i][j][e] + E[(size_t)(r & 63) * G3 + c];
        gi[(size_t)r * G3 + c] = f2bf(v);
      }
}

// ---------------- persistent recurrence kernel ----------------
// 128 wgs x 512 thr. wg = (cs, rh): 16 h-cols [cs*16,+16), 32 batch rows [rh*32,+32).
// 8 waves: (rt in 0..1) x (kq in 0..3): row-tile rt, K-slice kq*256.
// h exchange via agent-scope per-access atomics (no fences -> L2 stays warm).
// Barrier: per-wg flags (release) + wg0 poll + go word (relaxed spin).
__global__ __launch_bounds__(512) void k_rnn(
    const unsigned short* __restrict__ giE,   // [256*64][3072] bf16 (incl E)
    const unsigned short* __restrict__ Whhb,  // [3072][1024] bf16
    const float* __restrict__ b_hh,
    const float* __restrict__ h0,
    const int* __restrict__ length,
    unsigned short* __restrict__ hbuf,        // [2][64][1024] bf16
    float* __restrict__ h0row,                // [2][1024] f32 (exact h[0] row)
    float* __restrict__ out,                  // [256][64][1024] f32
    float* __restrict__ hn,                   // [64][1024] f32
    unsigned int* __restrict__ flags,         // 256 flags, spread *16 uints
    unsigned int* __restrict__ go) {
  __shared__ f32x4 red[1536];                 // [8 waves][3 strips][64 lanes] = 24 KB
  const int wg = blockIdx.x;
  const int cs = wg & 63, rh = wg >> 6;
  const int j0 = cs * 16, r0 = rh * 32;
  const int tid = threadIdx.x;
  const int w = tid >> 6, l = tid & 63, lo = l & 15, hi = l >> 4;
  const int rt = w >> 2, kq = w & 3;
  const bool upd = (kq == 0);
  const int col = j0 + lo;
  const int rowbase = r0 + rt * 16;

  const unsigned short* wrp0 = Whhb + (size_t)col * 1024;
  const unsigned short* wrp1 = Whhb + (size_t)(1024 + col) * 1024;
  const unsigned short* wrp2 = Whhb + (size_t)(2048 + col) * 1024;
  const float bhhn = b_hh[2048 + col];

  float hown[4] = {0.f, 0.f, 0.f, 0.f};
  float gir[3][4];
  int len4[4] = {0, 0, 0, 0};

  auto go_wait = [&](unsigned tgt) {
    if (wg == 0) {
      if (w == 0) {
        for (;;) {
          unsigned f0 = __hip_atomic_load(&flags[l * 16], __ATOMIC_RELAXED, __HIP_MEMORY_SCOPE_AGENT);
          unsigned f1 = __hip_atomic_load(&flags[(64 + l) * 16], __ATOMIC_RELAXED, __HIP_MEMORY_SCOPE_AGENT);
          unsigned f2 = __hip_atomic_load(&flags[(128 + l) * 16], __ATOMIC_RELAXED, __HIP_MEMORY_SCOPE_AGENT);
          unsigned f3 = __hip_atomic_load(&flags[(192 + l) * 16], __ATOMIC_RELAXED, __HIP_MEMORY_SCOPE_AGENT);
          if (__all((f0 >= tgt) && (f1 >= tgt) && (f2 >= tgt) && (f3 >= tgt))) break;
          __builtin_amdgcn_s_sleep(1);
        }
        if (l == 0) __hip_atomic_store(go, tgt, __ATOMIC_RELEASE, __HIP_MEMORY_SCOPE_AGENT);
      }
    } else if (tid == 0) {
      while (__hip_atomic_load(go, __ATOMIC_RELAXED, __HIP_MEMORY_SCOPE_AGENT) < tgt)
        __builtin_amdgcn_s_sleep(1);
    }
    __syncthreads();
  };

  // ---- init: load h0 state, publish h_0, signal, prefetch gi(0) ----
  if (upd) {
#pragma unroll
    for (int j = 0; j < 4; j++) {
      int b = rowbase + hi * 4 + j;
      hown[j] = h0[(size_t)b * 1024 + col];
      len4[j] = length[b];
    }
#pragma unroll
    for (int j = 0; j < 4; j++) {
      unsigned int mine = f2bf(hown[j]);
      unsigned int oth = __shfl_xor(mine, 1, 64);
      if (!(lo & 1)) {
        int b = rowbase + hi * 4 + j;
        __hip_atomic_store((unsigned int*)(hbuf + (size_t)b * 1024 + j0 + lo),
                           mine | (oth << 16), __ATOMIC_RELAXED, __HIP_MEMORY_SCOPE_AGENT);
      }
    }
    if (rh == 0 && rt == 0 && hi == 0)
      __hip_atomic_store(&h0row[col], hown[0], __ATOMIC_RELAXED, __HIP_MEMORY_SCOPE_AGENT);
    if (l == 0)
      __hip_atomic_store(&flags[(wg * 2 + rt) * 16], 1u, __ATOMIC_RELEASE, __HIP_MEMORY_SCOPE_AGENT);
#pragma unroll
    for (int s = 0; s < 3; s++)
#pragma unroll
      for (int j = 0; j < 4; j++)
        gir[s][j] = bf2f(giE[(size_t)(rowbase + hi * 4 + j) * G3 + s * 1024 + col]);
  }
  go_wait(1u);

  for (int t = 0; t < TT; t++) {
    const unsigned short* hb = hbuf + (size_t)(t & 1) * (BB * 1024);
    f32x4 a0 = {0.f, 0.f, 0.f, 0.f}, a1 = a0, a2 = a0;
#pragma unroll
    for (int kk = 0; kk < 8; kk++) {
      int k = kq * 256 + kk * 32 + hi * 8;
      const unsigned short* hp = hb + (size_t)(rowbase + lo) * 1024 + k;
      union { ull u[2]; short8 v; } a;
      a.u[0] = __hip_atomic_load((const ull*)hp, __ATOMIC_RELAXED, __HIP_MEMORY_SCOPE_AGENT);
      a.u[1] = __hip_atomic_load((const ull*)(hp + 4), __ATOMIC_RELAXED, __HIP_MEMORY_SCOPE_AGENT);
      short8 b0 = *(const short8*)(wrp0 + k);
      short8 b1 = *(const short8*)(wrp1 + k);
      short8 b2 = *(const short8*)(wrp2 + k);
      a0 = mfma16(a.v, b0, a0);
      a1 = mfma16(a.v, b1, a1);
      a2 = mfma16(a.v, b2, a2);
    }
    float h0p = 0.f;
    if (upd)
      h0p = __hip_atomic_load(&h0row[(t & 1) * 1024 + col], __ATOMIC_RELAXED, __HIP_MEMORY_SCOPE_AGENT);
    red[(w * 3 + 0) * 64 + l] = a0;
    red[(w * 3 + 1) * 64 + l] = a1;
    red[(w * 3 + 2) * 64 + l] = a2;
    __syncthreads();
    if (upd) {
      f32x4 fin[3];
#pragma unroll
      for (int s = 0; s < 3; s++) {
        f32x4 v = red[((rt * 4 + 0) * 3 + s) * 64 + l];
#pragma unroll
        for (int w2 = 1; w2 < 4; w2++) {
          f32x4 p = red[((rt * 4 + w2) * 3 + s) * 64 + l];
          v[0] += p[0]; v[1] += p[1]; v[2] += p[2]; v[3] += p[3];
        }
        fin[s] = v;
      }
      float hv[4];
#pragma unroll
      for (int j = 0; j < 4; j++) {
        float R = fin[0][j] + gir[0][j];
        float I = fin[1][j] + gir[1][j];
        float rg = 1.f / (1.f + __expf(-R));
        float ig = 1.f / (1.f + __expf(-I));
        float nx = gir[2][j] + rg * (fin[2][j] + bhhn);
        nx = fminf(15.f, fmaxf(-15.f, nx));
        float e2 = __expf(2.f * nx);
        float ng = (e2 - 1.f) / (e2 + 1.f);
        float hy = ng + ig * (hown[j] - ng);
        float res = (t < len4[j]) ? hy : h0p;
        hv[j] = res;
        hown[j] = res;
        int b = rowbase + hi * 4 + j;
        out[(size_t)t * (BB * HH) + (size_t)b * 1024 + col] = res;
        if (t == TT - 1) hn[(size_t)b * 1024 + col] = res;
      }
      if (t < TT - 1) {
        unsigned short* dst = hbuf + (size_t)((t + 1) & 1) * (BB * 1024);
#pragma unroll
        for (int j = 0; j < 4; j++) {
          unsigned int mine = f2bf(hv[j]);
          unsigned int oth = __shfl_xor(mine, 1, 64);
          if (!(lo & 1)) {
            int b = rowbase + hi * 4 + j;
            __hip_atomic_store((unsigned int*)(dst + (size_t)b * 1024 + j0 + lo),
                               mine | (oth << 16), __ATOMIC_RELAXED, __HIP_MEMORY_SCOPE_AGENT);
          }
        }
        if (rh == 0 && rt == 0 && hi == 0)
          __hip_atomic_store(&h0row[((t + 1) & 1) * 1024 + col], hv[0],
                             __ATOMIC_RELAXED, __HIP_MEMORY_SCOPE_AGENT);
        if (l == 0)
          __hip_atomic_store(&flags[(wg * 2 + rt) * 16], (unsigned)(t + 2),
                             __ATOMIC_RELEASE, __HIP_MEMORY_SCOPE_AGENT);
        // prefetch gi(t+1): HBM latency hides under the barrier spin
        const unsigned short* gb = giE + (size_t)(t + 1) * 64 * G3;
#pragma unroll
        for (int s = 0; s < 3; s++)
#pragma unroll
          for (int j = 0; j < 4; j++)
            gir[s][j] = bf2f(gb[(size_t)(rowbase + hi * 4 + j) * G3 + s * 1024 + col]);
      }
    }
    if (t == TT - 1) break;
    go_wait((unsigned)(t + 2));
  }
}

// ---------------- host ----------------
extern "C" void kernel_launch(void* const* d_in, const int* in_sizes, int n_in,
                              void* d_out, int out_size, void* d_ws, size_t ws_size,
                              hipStream_t stream) {
  const float* input_ = (const float*)d_in[0];
  const int* length   = (const int*)d_in[1];
  const float* h0     = (const float*)d_in[2];
  const float* cj     = (const float*)d_in[3];
  const float* he     = (const float*)d_in[4];
  const float* w_ih   = (const float*)d_in[5];
  const float* w_hh   = (const float*)d_in[6];
  const float* w_ch   = (const float*)d_in[7];
  const float* w_zh   = (const float*)d_in[8];
  const float* b_ih   = (const float*)d_in[9];
  const float* b_hh   = (const float*)d_in[10];
  const float* b_ch   = (const float*)d_in[11];
  const float* b_zh   = (const float*)d_in[12];

  char* ws = (char*)d_ws;
  const size_t OFF_GO    = 0;
  const size_t OFF_FLAGS = 1024;
  const size_t OFF_H0ROW = 20480;
  const size_t OFF_XB    = 32768;
  const size_t OFF_WIHB  = OFF_XB + 33554432ull;
  const size_t OFF_WHHB  = OFF_WIHB + 6291456ull;
  const size_t OFF_WCHB  = OFF_WHHB + 6291456ull;
  const size_t OFF_WZHB  = OFF_WCHB + 6291456ull;
  const size_t OFF_CJB   = OFF_WZHB + 6291456ull;
  const size_t OFF_HEB   = OFF_CJB + 131072ull;
  const size_t OFF_E     = OFF_HEB + 131072ull;
  const size_t OFF_GI    = OFF_E + 786432ull;
  const size_t OFF_HBUF  = OFF_GI + 100663296ull;

  unsigned int* go      = (unsigned int*)(ws + OFF_GO);
  unsigned int* flags   = (unsigned int*)(ws + OFF_FLAGS);
  float* h0row          = (float*)(ws + OFF_H0ROW);
  unsigned short* Xb    = (unsigned short*)(ws + OFF_XB);
  unsigned short* Wihb  = (unsigned short*)(ws + OFF_WIHB);
  unsigned short* Whhb  = (unsigned short*)(ws + OFF_WHHB);
  unsigned short* Wchb  = (unsigned short*)(ws + OFF_WCHB);
  unsigned short* Wzhb  = (unsigned short*)(ws + OFF_WZHB);
  unsigned short* cjb   = (unsigned short*)(ws + OFF_CJB);
  unsigned short* heb   = (unsigned short*)(ws + OFF_HEB);
  float* E              = (float*)(ws + OFF_E);
  unsigned short* gi    = (unsigned short*)(ws + OFF_GI);
  unsigned short* hbuf  = (unsigned short*)(ws + OFF_HBUF);

  float* out = (float*)d_out;
  float* hn  = out + 16777216;   // T*B*H

  hipMemsetAsync(ws, 0, 32768, stream);   // go + flags (+slack)
  k_cvt_bf16<<<2048, 256, 0, stream>>>(input_, Xb, 16777216 / 4);
  k_cvt_bf16<<<1024, 256, 0, stream>>>(w_ih, Wihb, 3145728 / 4);
  k_cvt_bf16<<<1024, 256, 0, stream>>>(w_hh, Whhb, 3145728 / 4);
  k_cvt_bf16<<<1024, 256, 0, stream>>>(w_ch, Wchb, 3145728 / 4);
  k_cvt_bf16<<<1024, 256, 0, stream>>>(w_zh, Wzhb, 3145728 / 4);
  k_cvt_bf16<<<64, 256, 0, stream>>>(cj, cjb, 65536 / 4);
  k_cvt_bf16<<<64, 256, 0, stream>>>(he, heb, 65536 / 4);
  k_ctx<<<192, 256, 0, stream>>>(cjb, heb, Wchb, Wzhb, b_ih, b_hh, b_ch, b_zh, E);
  k_gemm_gi<<<3072, 256, 0, stream>>>(Xb, Wihb, E, gi);
  k_rnn<<<128, 512, 0, stream>>>(gi, Whhb, b_hh, h0, length, hbuf, h0row, out, hn, flags, go);
}